// Round 3
// baseline (5707.267 us; speedup 1.0000x reference)
//
#include <hip/hip_runtime.h>
#include <hip/hip_bf16.h>
#include <stdint.h>

typedef unsigned short u16;
typedef unsigned int   u32;

// ---------- bf16 helpers (raw-bit, RNE store) ----------
__device__ __forceinline__ float b2f(u32 u) {
    union { u32 i; float f; } v;
    v.i = u << 16;
    return v.f;
}
__device__ __forceinline__ u16 f2b(float f) {
    union { float f; u32 i; } v; v.f = f;
    u32 x = v.i;
    x += 0x7fffu + ((x >> 16) & 1u);   // round-to-nearest-even
    return (u16)(x >> 16);
}

// ---------- GEMM: C[M,N] = A[M,K] @ B[K,N] + bias[N]; A,B,bias fp32; C = OT ----------
// BM=BN=128, BK=16, 256 threads, 8x8 microtile per thread, fp32 accumulate.
template<typename OT, int BM, int BN, int BK>
__global__ __launch_bounds__(256)
void gemm_bias(const float* __restrict__ A, const float* __restrict__ B,
               const float* __restrict__ bias, OT* __restrict__ C,
               int M, int N, int K)
{
    __shared__ float As[BK][BM];   // transposed: As[k][m]
    __shared__ float Bs[BK][BN];

    const int tid = threadIdx.x;
    const int m0 = blockIdx.y * BM;
    const int n0 = blockIdx.x * BN;
    const int tm = tid >> 4;            // 0..15 -> rows tm*8..+7
    const int tn = tid & 15;            // 0..15 -> cols tn*8..+7

    // A tile loader: 128 rows x 16 cols, 8 floats per thread
    const int arow = tid >> 1;          // 0..127
    const int acol = (tid & 1) * 8;     // 0 or 8
    // B tile loader: 16 rows x 128 cols, 8 floats per thread
    const int brow = tid >> 4;          // 0..15
    const int bcol = (tid & 15) * 8;    // 0..120

    const float* Ap = A + (size_t)(m0 + arow) * K + acol;
    const float* Bp = B + (size_t)brow * N + n0 + bcol;

    float acc[8][8];
#pragma unroll
    for (int i = 0; i < 8; i++)
#pragma unroll
        for (int j = 0; j < 8; j++) acc[i][j] = 0.f;

    for (int k0 = 0; k0 < K; k0 += BK) {
        const float4 a0 = *reinterpret_cast<const float4*>(Ap + k0);
        const float4 a1 = *reinterpret_cast<const float4*>(Ap + k0 + 4);
        const float4 b0 = *reinterpret_cast<const float4*>(Bp + (size_t)k0 * N);
        const float4 b1 = *reinterpret_cast<const float4*>(Bp + (size_t)k0 * N + 4);
        __syncthreads();   // previous iteration's LDS reads done
        As[acol + 0][arow] = a0.x; As[acol + 1][arow] = a0.y;
        As[acol + 2][arow] = a0.z; As[acol + 3][arow] = a0.w;
        As[acol + 4][arow] = a1.x; As[acol + 5][arow] = a1.y;
        As[acol + 6][arow] = a1.z; As[acol + 7][arow] = a1.w;
        *reinterpret_cast<float4*>(&Bs[brow][bcol])     = b0;
        *reinterpret_cast<float4*>(&Bs[brow][bcol + 4]) = b1;
        __syncthreads();
#pragma unroll
        for (int kk = 0; kk < BK; kk++) {
            float ar[8], br[8];
            *(float4*)&ar[0] = *(const float4*)&As[kk][tm * 8];
            *(float4*)&ar[4] = *(const float4*)&As[kk][tm * 8 + 4];
            *(float4*)&br[0] = *(const float4*)&Bs[kk][tn * 8];
            *(float4*)&br[4] = *(const float4*)&Bs[kk][tn * 8 + 4];
#pragma unroll
            for (int i = 0; i < 8; i++)
#pragma unroll
                for (int j = 0; j < 8; j++)
                    acc[i][j] = fmaf(ar[i], br[j], acc[i][j]);
        }
    }

    // epilogue: + bias, store as OT (bf16 packed or fp32 vectors)
#pragma unroll
    for (int i = 0; i < 8; i++) {
        const int row = m0 + tm * 8 + i;
        float v[8];
#pragma unroll
        for (int j = 0; j < 8; j++)
            v[j] = acc[i][j] + bias[n0 + tn * 8 + j];

        if constexpr (sizeof(OT) == 2) {
            u16* cp = (u16*)C + (size_t)row * N + n0 + tn * 8;
            u32 packed[4];
#pragma unroll
            for (int j = 0; j < 4; j++)
                packed[j] = (u32)f2b(v[2*j]) | ((u32)f2b(v[2*j + 1]) << 16);
            *reinterpret_cast<uint4*>(cp) = make_uint4(packed[0], packed[1], packed[2], packed[3]);
        } else {
            float* cp = (float*)C + (size_t)row * N + n0 + tn * 8;
            *reinterpret_cast<float4*>(cp)     = make_float4(v[0], v[1], v[2], v[3]);
            *reinterpret_cast<float4*>(cp + 4) = make_float4(v[4], v[5], v[6], v[7]);
        }
    }
}

// ---------- Attention: one block per (b, h, q) row; scores in LDS ----------
// qkv layout: [B, T, 3C] bf16 (Q at +0, K at +C, V at +2C); out: [B, T, C] fp32
__global__ __launch_bounds__(256)
void attn(const u16* __restrict__ qkv, float* __restrict__ out)
{
    constexpr int T = 2048, C = 1024, C3 = 3072, H = 16;
    __shared__ float qv[64];
    __shared__ float sc[T];
    __shared__ float red[8];
    __shared__ float osum[4][64];

    const int tid = threadIdx.x;
    const int q   = blockIdx.x & (T - 1);
    const int bh  = blockIdx.x >> 11;        // / 2048
    const int h   = bh & (H - 1);
    const int b   = bh >> 4;

    // load Q row into LDS (fp32)
    if (tid < 64) qv[tid] = b2f(qkv[(size_t)(b * T + q) * C3 + h * 64 + tid]);
    __syncthreads();

    // pass 1: scores for keys 0..q, track local max
    float mloc = -INFINITY;
    for (int k = tid; k <= q; k += 256) {
        const uint4* kp = reinterpret_cast<const uint4*>(
            qkv + (size_t)(b * T + k) * C3 + C + h * 64);
        float s = 0.f;
#pragma unroll
        for (int i = 0; i < 8; i++) {
            const uint4 u = kp[i];
            const int d = i * 8;
            s += b2f(u.x & 0xffffu) * qv[d]     + b2f(u.x >> 16) * qv[d + 1];
            s += b2f(u.y & 0xffffu) * qv[d + 2] + b2f(u.y >> 16) * qv[d + 3];
            s += b2f(u.z & 0xffffu) * qv[d + 4] + b2f(u.z >> 16) * qv[d + 5];
            s += b2f(u.w & 0xffffu) * qv[d + 6] + b2f(u.w >> 16) * qv[d + 7];
        }
        s *= 0.125f;   // 1/sqrt(64)
        sc[k] = s;
        mloc = fmaxf(mloc, s);
    }
    // block-reduce max (wave=64: offsets 32..1)
#pragma unroll
    for (int off = 32; off > 0; off >>= 1)
        mloc = fmaxf(mloc, __shfl_down(mloc, off));
    if ((tid & 63) == 0) red[tid >> 6] = mloc;
    __syncthreads();
    if (tid == 0)
        red[0] = fmaxf(fmaxf(red[0], red[1]), fmaxf(red[2], red[3]));
    __syncthreads();
    const float m = red[0];

    // pass 1b: exp + sum
    float lloc = 0.f;
    for (int k = tid; k <= q; k += 256) {
        const float p = __expf(sc[k] - m);
        sc[k] = p;
        lloc += p;
    }
#pragma unroll
    for (int off = 32; off > 0; off >>= 1)
        lloc += __shfl_down(lloc, off);
    if ((tid & 63) == 0) red[4 + (tid >> 6)] = lloc;
    __syncthreads();
    if (tid == 0) red[4] = red[4] + red[5] + red[6] + red[7];
    __syncthreads();
    const float invl = 1.0f / red[4];

    // pass 2: o[d] = sum_k p[k] * V[k][d]; wave w handles k ≡ w (mod 4), lane = d
    const int d   = tid & 63;
    const int seg = tid >> 6;
    float o = 0.f;
    for (int k = seg; k <= q; k += 4)
        o += sc[k] * b2f(qkv[(size_t)(b * T + k) * C3 + 2 * C + h * 64 + d]);
    osum[seg][d] = o;
    __syncthreads();
    if (tid < 64) {
        const float r = (osum[0][tid] + osum[1][tid] + osum[2][tid] + osum[3][tid]) * invl;
        out[(size_t)(b * T + q) * C + h * 64 + tid] = r;
    }
}

// ---------- launcher ----------
extern "C" void kernel_launch(void* const* d_in, const int* in_sizes, int n_in,
                              void* d_out, int out_size, void* d_ws, size_t ws_size,
                              hipStream_t stream)
{
    constexpr int B = 4, T = 2048, C = 1024;
    constexpr int M = B * T;          // 8192
    const float* x      = (const float*)d_in[0];
    const float* W_attn = (const float*)d_in[1];
    const float* b_attn = (const float*)d_in[2];
    const float* W_proj = (const float*)d_in[3];
    const float* b_proj = (const float*)d_in[4];
    float* out = (float*)d_out;   // reference output dtype is float32

    u16*   qkv    = (u16*)d_ws;                                   // [8192,3072] bf16 = 50.3 MB
    float* attn_o = (float*)((char*)d_ws + (size_t)M * 3 * C * sizeof(u16)); // [8192,1024] fp32 = 33.6 MB

    // 1) qkv = x @ W_attn + b_attn   (fp32 in, bf16 out)
    gemm_bias<u16, 128, 128, 16><<<dim3(3 * C / 128, M / 128), 256, 0, stream>>>(
        x, W_attn, b_attn, qkv, M, 3 * C, C);

    // 2) causal softmax attention per (b, h, q)  (bf16 qkv in, fp32 out)
    attn<<<dim3(B * 16 * T), 256, 0, stream>>>(qkv, attn_o);

    // 3) out = attn_o @ W_proj + b_proj   (fp32 in, fp32 out)
    gemm_bias<float, 128, 128, 16><<<dim3(C / 128, M / 128), 256, 0, stream>>>(
        attn_o, W_proj, b_proj, out, M, C, C);
}

// Round 4
// 1160.174 us; speedup vs baseline: 4.9193x; 4.9193x over previous
//
#include <hip/hip_runtime.h>
#include <hip/hip_bf16.h>
#include <stdint.h>

typedef unsigned short u16;
typedef unsigned int   u32;

using short8 = __attribute__((ext_vector_type(8))) short;
using f32x4  = __attribute__((ext_vector_type(4))) float;

// ---------- bf16 helpers (raw-bit, RNE store) ----------
__device__ __forceinline__ float b2f(u32 u) {
    union { u32 i; float f; } v;
    v.i = u << 16;
    return v.f;
}
__device__ __forceinline__ u16 f2b(float f) {
    union { float f; u32 i; } v; v.f = f;
    u32 x = v.i;
    x += 0x7fffu + ((x >> 16) & 1u);   // round-to-nearest-even
    return (u16)(x >> 16);
}

// ---------- GEMM: C[M,N] = A[M,K] @ B[K,N] + bias[N]; A,B,bias fp32; C = OT ----------
template<typename OT, int BM, int BN, int BK>
__global__ __launch_bounds__(256)
void gemm_bias(const float* __restrict__ A, const float* __restrict__ B,
               const float* __restrict__ bias, OT* __restrict__ C,
               int M, int N, int K)
{
    __shared__ float As[BK][BM];   // transposed: As[k][m]
    __shared__ float Bs[BK][BN];

    const int tid = threadIdx.x;
    const int m0 = blockIdx.y * BM;
    const int n0 = blockIdx.x * BN;
    const int tm = tid >> 4;
    const int tn = tid & 15;

    const int arow = tid >> 1;
    const int acol = (tid & 1) * 8;
    const int brow = tid >> 4;
    const int bcol = (tid & 15) * 8;

    const float* Ap = A + (size_t)(m0 + arow) * K + acol;
    const float* Bp = B + (size_t)brow * N + n0 + bcol;

    float acc[8][8];
#pragma unroll
    for (int i = 0; i < 8; i++)
#pragma unroll
        for (int j = 0; j < 8; j++) acc[i][j] = 0.f;

    for (int k0 = 0; k0 < K; k0 += BK) {
        const float4 a0 = *reinterpret_cast<const float4*>(Ap + k0);
        const float4 a1 = *reinterpret_cast<const float4*>(Ap + k0 + 4);
        const float4 b0 = *reinterpret_cast<const float4*>(Bp + (size_t)k0 * N);
        const float4 b1 = *reinterpret_cast<const float4*>(Bp + (size_t)k0 * N + 4);
        __syncthreads();
        As[acol + 0][arow] = a0.x; As[acol + 1][arow] = a0.y;
        As[acol + 2][arow] = a0.z; As[acol + 3][arow] = a0.w;
        As[acol + 4][arow] = a1.x; As[acol + 5][arow] = a1.y;
        As[acol + 6][arow] = a1.z; As[acol + 7][arow] = a1.w;
        *reinterpret_cast<float4*>(&Bs[brow][bcol])     = b0;
        *reinterpret_cast<float4*>(&Bs[brow][bcol + 4]) = b1;
        __syncthreads();
#pragma unroll
        for (int kk = 0; kk < BK; kk++) {
            float ar[8], br[8];
            *(float4*)&ar[0] = *(const float4*)&As[kk][tm * 8];
            *(float4*)&ar[4] = *(const float4*)&As[kk][tm * 8 + 4];
            *(float4*)&br[0] = *(const float4*)&Bs[kk][tn * 8];
            *(float4*)&br[4] = *(const float4*)&Bs[kk][tn * 8 + 4];
#pragma unroll
            for (int i = 0; i < 8; i++)
#pragma unroll
                for (int j = 0; j < 8; j++)
                    acc[i][j] = fmaf(ar[i], br[j], acc[i][j]);
        }
    }

#pragma unroll
    for (int i = 0; i < 8; i++) {
        const int row = m0 + tm * 8 + i;
        float v[8];
#pragma unroll
        for (int j = 0; j < 8; j++)
            v[j] = acc[i][j] + bias[n0 + tn * 8 + j];

        if constexpr (sizeof(OT) == 2) {
            u16* cp = (u16*)C + (size_t)row * N + n0 + tn * 8;
            u32 packed[4];
#pragma unroll
            for (int j = 0; j < 4; j++)
                packed[j] = (u32)f2b(v[2*j]) | ((u32)f2b(v[2*j + 1]) << 16);
            *reinterpret_cast<uint4*>(cp) = make_uint4(packed[0], packed[1], packed[2], packed[3]);
        } else {
            float* cp = (float*)C + (size_t)row * N + n0 + tn * 8;
            *reinterpret_cast<float4*>(cp)     = make_float4(v[0], v[1], v[2], v[3]);
            *reinterpret_cast<float4*>(cp + 4) = make_float4(v[4], v[5], v[6], v[7]);
        }
    }
}

// ---------- Flash attention (bf16 MFMA 16x16x32), causal ----------
// qkv: [B, T, 3C] bf16 (Q +0, K +C, V +2C). out: [B, T, C] fp32.
// Block: 256 threads = 4 waves; 64 q-rows per block (16 per wave); k-tiles of 64.
__global__ __launch_bounds__(256)
void attn_flash(const u16* __restrict__ qkv, float* __restrict__ out)
{
    constexpr int T = 2048, C = 1024, C3 = 3072;
    constexpr int QT = 64, KT = 64, LDP = 72;   // LDS row pad: 72 u16 = 144 B

    __shared__ u16 Ks[KT][LDP];       // K-tile row-major [key][d]
    __shared__ u16 Vt[64][LDP];       // V-tile transposed [d][key]
    __shared__ u16 Pl[4][16][LDP];    // per-wave P round-trip [q][key]

    const int tid  = threadIdx.x;
    const int w    = tid >> 6;        // wave 0..3
    const int lane = tid & 63;
    const int quad = lane >> 4;       // 0..3
    const int col  = lane & 15;       // 0..15

    const int qt = (T / QT - 1) - blockIdx.x;   // reversed: heavy blocks first
    const int bh = blockIdx.y;
    const int h  = bh & 15;
    const int b  = bh >> 4;
    const int Q0 = qt * QT;

    const size_t rowQ = (size_t)(b * T + Q0 + w * 16 + col) * C3 + h * 64;

    // persistent Q fragments (contraction d: c*32 + quad*8 + j)
    short8 qfrag[2];
    qfrag[0] = *reinterpret_cast<const short8*>(qkv + rowQ + 0 * 32 + quad * 8);
    qfrag[1] = *reinterpret_cast<const short8*>(qkv + rowQ + 1 * 32 + quad * 8);

    f32x4 Oacc[4];
#pragma unroll
    for (int d = 0; d < 4; d++) Oacc[d] = (f32x4){0.f, 0.f, 0.f, 0.f};
    float m_i[4], l_i[4];
#pragma unroll
    for (int r = 0; r < 4; r++) { m_i[r] = -INFINITY; l_i[r] = 0.f; }

    for (int kt = 0; kt <= qt; kt++) {
        const int kt0 = kt * KT;
        __syncthreads();   // previous tile's LDS reads complete

        // ---- stage K tile: thread t -> row t>>2, cols (t&3)*16..+15
        {
            const int r = tid >> 2, cg = (tid & 3) * 16;
            const uint4* gp = reinterpret_cast<const uint4*>(
                qkv + (size_t)(b * T + kt0 + r) * C3 + C + h * 64 + cg);
            *reinterpret_cast<uint4*>(&Ks[r][cg])     = gp[0];
            *reinterpret_cast<uint4*>(&Ks[r][cg + 8]) = gp[1];
        }
        // ---- stage V transposed: thread t -> keys 2kp,2kp+1 (kp=t>>3), d = (t&7)*8..+7
        {
            const int kp = tid >> 3, dg = (tid & 7) * 8;
            const u16* g0 = qkv + (size_t)(b * T + kt0 + 2 * kp) * C3 + 2 * C + h * 64 + dg;
            uint4 v0 = *reinterpret_cast<const uint4*>(g0);
            uint4 v1 = *reinterpret_cast<const uint4*>(g0 + C3);
            const u16* p0 = reinterpret_cast<const u16*>(&v0);
            const u16* p1 = reinterpret_cast<const u16*>(&v1);
#pragma unroll
            for (int i = 0; i < 8; i++)
                *reinterpret_cast<u32*>(&Vt[dg + i][2 * kp]) =
                    (u32)p0[i] | ((u32)p1[i] << 16);
        }
        __syncthreads();

        // ---- S = Q K^T for 4 subtiles of 16 keys
        f32x4 s[4];
#pragma unroll
        for (int sub = 0; sub < 4; sub++) {
            short8 kf0 = *reinterpret_cast<const short8*>(&Ks[sub * 16 + col][0 * 32 + quad * 8]);
            short8 kf1 = *reinterpret_cast<const short8*>(&Ks[sub * 16 + col][1 * 32 + quad * 8]);
            f32x4 acc = (f32x4){0.f, 0.f, 0.f, 0.f};
            acc = __builtin_amdgcn_mfma_f32_16x16x32_bf16(qfrag[0], kf0, acc, 0, 0, 0);
            acc = __builtin_amdgcn_mfma_f32_16x16x32_bf16(qfrag[1], kf1, acc, 0, 0, 0);
#pragma unroll
            for (int r = 0; r < 4; r++) acc[r] *= 0.125f;   // 1/sqrt(64)
            s[sub] = acc;
        }

        // ---- causal mask (diagonal tile only)
        if (kt == qt) {
#pragma unroll
            for (int sub = 0; sub < 4; sub++)
#pragma unroll
                for (int r = 0; r < 4; r++) {
                    const int kglob = kt0 + sub * 16 + col;
                    const int qglob = Q0 + w * 16 + quad * 4 + r;
                    if (kglob > qglob) s[sub][r] = -INFINITY;
                }
        }

        // ---- online softmax (rows live on (quad, r); reduce across 16 cols)
        float mnew[4], al[4], rs[4];
#pragma unroll
        for (int r = 0; r < 4; r++) {
            float t0 = fmaxf(fmaxf(s[0][r], s[1][r]), fmaxf(s[2][r], s[3][r]));
            t0 = fmaxf(t0, __shfl_xor(t0, 1));
            t0 = fmaxf(t0, __shfl_xor(t0, 2));
            t0 = fmaxf(t0, __shfl_xor(t0, 4));
            t0 = fmaxf(t0, __shfl_xor(t0, 8));
            mnew[r] = fmaxf(m_i[r], t0);
            al[r]   = __expf(m_i[r] - mnew[r]);
            m_i[r]  = mnew[r];
        }
#pragma unroll
        for (int sub = 0; sub < 4; sub++)
#pragma unroll
            for (int r = 0; r < 4; r++)
                s[sub][r] = __expf(s[sub][r] - mnew[r]);
#pragma unroll
        for (int r = 0; r < 4; r++) {
            float t0 = s[0][r] + s[1][r] + s[2][r] + s[3][r];
            t0 += __shfl_xor(t0, 1);
            t0 += __shfl_xor(t0, 2);
            t0 += __shfl_xor(t0, 4);
            t0 += __shfl_xor(t0, 8);
            rs[r]  = t0;
            l_i[r] = l_i[r] * al[r] + rs[r];
        }
        // rescale O accumulators
#pragma unroll
        for (int d = 0; d < 4; d++)
#pragma unroll
            for (int r = 0; r < 4; r++)
                Oacc[d][r] *= al[r];

        // ---- P: C-layout -> LDS (bf16) -> A-layout
#pragma unroll
        for (int sub = 0; sub < 4; sub++)
#pragma unroll
            for (int r = 0; r < 4; r++)
                Pl[w][quad * 4 + r][sub * 16 + col] = f2b(s[sub][r]);
        __syncthreads();   // DS write->read ordering (uniform across waves)

        // ---- O += P V  (contraction over 64 keys = 2 chunks of 32)
#pragma unroll
        for (int dsub = 0; dsub < 4; dsub++) {
#pragma unroll
            for (int c = 0; c < 2; c++) {
                short8 pf = *reinterpret_cast<const short8*>(&Pl[w][col][c * 32 + quad * 8]);
                short8 vf = *reinterpret_cast<const short8*>(&Vt[dsub * 16 + col][c * 32 + quad * 8]);
                Oacc[dsub] = __builtin_amdgcn_mfma_f32_16x16x32_bf16(pf, vf, Oacc[dsub], 0, 0, 0);
            }
        }
    }

    // ---- epilogue: divide by l, write fp32
    float inv[4];
#pragma unroll
    for (int r = 0; r < 4; r++) inv[r] = 1.0f / l_i[r];
#pragma unroll
    for (int dsub = 0; dsub < 4; dsub++)
#pragma unroll
        for (int r = 0; r < 4; r++) {
            const int qglob = Q0 + w * 16 + quad * 4 + r;
            out[(size_t)(b * T + qglob) * C + h * 64 + dsub * 16 + col] = Oacc[dsub][r] * inv[r];
        }
}

// ---------- launcher ----------
extern "C" void kernel_launch(void* const* d_in, const int* in_sizes, int n_in,
                              void* d_out, int out_size, void* d_ws, size_t ws_size,
                              hipStream_t stream)
{
    constexpr int B = 4, T = 2048, C = 1024;
    constexpr int M = B * T;          // 8192
    const float* x      = (const float*)d_in[0];
    const float* W_attn = (const float*)d_in[1];
    const float* b_attn = (const float*)d_in[2];
    const float* W_proj = (const float*)d_in[3];
    const float* b_proj = (const float*)d_in[4];
    float* out = (float*)d_out;

    u16*   qkv    = (u16*)d_ws;                                              // [8192,3072] bf16
    float* attn_o = (float*)((char*)d_ws + (size_t)M * 3 * C * sizeof(u16)); // [8192,1024] fp32

    // 1) qkv = x @ W_attn + b_attn   (fp32 in, bf16 out)
    gemm_bias<u16, 128, 128, 16><<<dim3(3 * C / 128, M / 128), 256, 0, stream>>>(
        x, W_attn, b_attn, qkv, M, 3 * C, C);

    // 2) causal flash attention (bf16 MFMA)
    attn_flash<<<dim3(T / 64, B * 16), 256, 0, stream>>>(qkv, attn_o);

    // 3) out = attn_o @ W_proj + b_proj   (fp32 in, fp32 out)
    gemm_bias<float, 128, 128, 16><<<dim3(C / 128, M / 128), 256, 0, stream>>>(
        attn_o, W_proj, b_proj, out, M, C, C);
}

// Round 5
// 463.880 us; speedup vs baseline: 12.3033x; 2.5010x over previous
//
#include <hip/hip_runtime.h>
#include <hip/hip_bf16.h>
#include <stdint.h>

typedef unsigned short u16;
typedef unsigned int   u32;

using short8 = __attribute__((ext_vector_type(8))) short;
using f32x4  = __attribute__((ext_vector_type(4))) float;

// ---------- bf16 helpers (raw-bit, RNE store) ----------
__device__ __forceinline__ float b2f(u32 u) {
    union { u32 i; float f; } v;
    v.i = u << 16;
    return v.f;
}
__device__ __forceinline__ u16 f2b(float f) {
    union { float f; u32 i; } v; v.f = f;
    u32 x = v.i;
    x += 0x7fffu + ((x >> 16) & 1u);   // round-to-nearest-even
    return (u16)(x >> 16);
}

// ---------- async global->LDS, 16B per lane ----------
__device__ __forceinline__ void gll16(const u16* g, u16* l) {
    __builtin_amdgcn_global_load_lds(
        (const __attribute__((address_space(1))) void*)g,
        (__attribute__((address_space(3))) void*)l, 16, 0, 0);
}

// ---------- prep: fp32 -> bf16 elementwise (8 elems/thread) ----------
__global__ __launch_bounds__(256)
void cast_bf16(const float* __restrict__ in, u16* __restrict__ out, int n)
{
    const int i = (blockIdx.x * 256 + threadIdx.x) * 8;
    if (i >= n) return;
    const float4 a = *reinterpret_cast<const float4*>(in + i);
    const float4 b = *reinterpret_cast<const float4*>(in + i + 4);
    u32 p0 = (u32)f2b(a.x) | ((u32)f2b(a.y) << 16);
    u32 p1 = (u32)f2b(a.z) | ((u32)f2b(a.w) << 16);
    u32 p2 = (u32)f2b(b.x) | ((u32)f2b(b.y) << 16);
    u32 p3 = (u32)f2b(b.z) | ((u32)f2b(b.w) << 16);
    *reinterpret_cast<uint4*>(out + i) = make_uint4(p0, p1, p2, p3);
}

// ---------- prep: W[R,Ncols] fp32 -> Wt[Ncols,R] bf16 (32x32 LDS tiles) ----------
__global__ __launch_bounds__(256)
void transpose_cast(const float* __restrict__ W, u16* __restrict__ Wt, int R, int Ncols)
{
    __shared__ float t[32][33];
    const int c0 = blockIdx.x * 32, r0 = blockIdx.y * 32;
    const int lx = threadIdx.x & 31, ly = threadIdx.x >> 5;   // 32 x 8
#pragma unroll
    for (int i = 0; i < 4; i++) {
        const int r = ly + i * 8;
        t[r][lx] = W[(size_t)(r0 + r) * Ncols + c0 + lx];
    }
    __syncthreads();
#pragma unroll
    for (int i = 0; i < 4; i++) {
        const int c = ly + i * 8;
        Wt[(size_t)(c0 + c) * R + r0 + lx] = f2b(t[lx][c]);
    }
}

// ---------- MFMA GEMM: C[M,N] = A[M,K] @ Bt[N,K]^T + bias[N] ----------
// A, Bt bf16; bias fp32; C = OT (u16 -> bf16 store, float -> fp32 store).
// 128x128 tile, BK=32, 256 threads = 4 waves, 4x4 16x16 acc per wave. m97 structure.
template<typename OT>
__global__ __launch_bounds__(256)
void gemm_mfma(const u16* __restrict__ A, const u16* __restrict__ Bt,
               const float* __restrict__ bias, OT* __restrict__ C,
               int M, int N, int K)
{
    __shared__ u16 As[128 * 32];   // [row][k], row stride 32
    __shared__ u16 Bs[128 * 32];   // [col][k]

    const int tid  = threadIdx.x;
    const int w    = tid >> 6;
    const int lane = tid & 63;
    const int quad = lane >> 4;
    const int c16  = lane & 15;
    const int wr   = w >> 1, wc = w & 1;

    const int m0 = blockIdx.y * 128;
    const int n0 = blockIdx.x * 128;

    // staging addresses: wave w covers rows w*32..+31 (2 loads of 16 rows)
    const int srow = w * 32 + (lane >> 2);
    const int skc  = (lane & 3) * 8;
    const u16* gA = A  + (size_t)(m0 + srow) * K + skc;
    const u16* gB = Bt + (size_t)(n0 + srow) * K + skc;
    u16* lA = As + w * 32 * 32 + lane * 8;   // byte: w*2048 + lane*16
    u16* lB = Bs + w * 32 * 32 + lane * 8;

    f32x4 acc[4][4];
#pragma unroll
    for (int i = 0; i < 4; i++)
#pragma unroll
        for (int j = 0; j < 4; j++) acc[i][j] = (f32x4){0.f, 0.f, 0.f, 0.f};

    for (int k0 = 0; k0 < K; k0 += 32) {
        __syncthreads();                 // previous iteration's ds_reads done
        gll16(gA + k0,            lA);
        gll16(gA + k0 + 16 * (size_t)K, lA + 16 * 32);
        gll16(gB + k0,            lB);
        gll16(gB + k0 + 16 * (size_t)K, lB + 16 * 32);
        __syncthreads();                 // drains vmcnt; LDS visible

        short8 af[4], bf[4];
#pragma unroll
        for (int i = 0; i < 4; i++)
            af[i] = *reinterpret_cast<const short8*>(&As[(wr * 64 + i * 16 + c16) * 32 + quad * 8]);
#pragma unroll
        for (int j = 0; j < 4; j++)
            bf[j] = *reinterpret_cast<const short8*>(&Bs[(wc * 64 + j * 16 + c16) * 32 + quad * 8]);
#pragma unroll
        for (int i = 0; i < 4; i++)
#pragma unroll
            for (int j = 0; j < 4; j++)
                acc[i][j] = __builtin_amdgcn_mfma_f32_16x16x32_bf16(af[i], bf[j], acc[i][j], 0, 0, 0);
    }

    // epilogue: C-layout row = quad*4 + r, col = c16
#pragma unroll
    for (int i = 0; i < 4; i++)
#pragma unroll
        for (int j = 0; j < 4; j++) {
            const int colg = n0 + wc * 64 + j * 16 + c16;
            const float bv = bias[colg];
#pragma unroll
            for (int r = 0; r < 4; r++) {
                const int rowg = m0 + wr * 64 + i * 16 + quad * 4 + r;
                const float v = acc[i][j][r] + bv;
                if constexpr (sizeof(OT) == 2)
                    ((u16*)C)[(size_t)rowg * N + colg] = f2b(v);
                else
                    ((float*)C)[(size_t)rowg * N + colg] = v;
            }
        }
}

// ---------- Flash attention (bf16 MFMA 16x16x32), causal; bf16 output ----------
__global__ __launch_bounds__(256)
void attn_flash(const u16* __restrict__ qkv, u16* __restrict__ out)
{
    constexpr int T = 2048, C = 1024, C3 = 3072;
    constexpr int QT = 64, KT = 64, LDP = 72;

    __shared__ u16 Ks[KT][LDP];
    __shared__ u16 Vt[64][LDP];
    __shared__ u16 Pl[4][16][LDP];

    const int tid  = threadIdx.x;
    const int w    = tid >> 6;
    const int lane = tid & 63;
    const int quad = lane >> 4;
    const int col  = lane & 15;

    const int qt = (T / QT - 1) - blockIdx.x;
    const int bh = blockIdx.y;
    const int h  = bh & 15;
    const int b  = bh >> 4;
    const int Q0 = qt * QT;

    const size_t rowQ = (size_t)(b * T + Q0 + w * 16 + col) * C3 + h * 64;

    short8 qfrag[2];
    qfrag[0] = *reinterpret_cast<const short8*>(qkv + rowQ + 0 * 32 + quad * 8);
    qfrag[1] = *reinterpret_cast<const short8*>(qkv + rowQ + 1 * 32 + quad * 8);

    f32x4 Oacc[4];
#pragma unroll
    for (int d = 0; d < 4; d++) Oacc[d] = (f32x4){0.f, 0.f, 0.f, 0.f};
    float m_i[4], l_i[4];
#pragma unroll
    for (int r = 0; r < 4; r++) { m_i[r] = -INFINITY; l_i[r] = 0.f; }

    for (int kt = 0; kt <= qt; kt++) {
        const int kt0 = kt * KT;
        __syncthreads();

        {
            const int r = tid >> 2, cg = (tid & 3) * 16;
            const uint4* gp = reinterpret_cast<const uint4*>(
                qkv + (size_t)(b * T + kt0 + r) * C3 + C + h * 64 + cg);
            *reinterpret_cast<uint4*>(&Ks[r][cg])     = gp[0];
            *reinterpret_cast<uint4*>(&Ks[r][cg + 8]) = gp[1];
        }
        {
            const int kp = tid >> 3, dg = (tid & 7) * 8;
            const u16* g0 = qkv + (size_t)(b * T + kt0 + 2 * kp) * C3 + 2 * C + h * 64 + dg;
            uint4 v0 = *reinterpret_cast<const uint4*>(g0);
            uint4 v1 = *reinterpret_cast<const uint4*>(g0 + C3);
            const u16* p0 = reinterpret_cast<const u16*>(&v0);
            const u16* p1 = reinterpret_cast<const u16*>(&v1);
#pragma unroll
            for (int i = 0; i < 8; i++)
                *reinterpret_cast<u32*>(&Vt[dg + i][2 * kp]) =
                    (u32)p0[i] | ((u32)p1[i] << 16);
        }
        __syncthreads();

        f32x4 s[4];
#pragma unroll
        for (int sub = 0; sub < 4; sub++) {
            short8 kf0 = *reinterpret_cast<const short8*>(&Ks[sub * 16 + col][0 * 32 + quad * 8]);
            short8 kf1 = *reinterpret_cast<const short8*>(&Ks[sub * 16 + col][1 * 32 + quad * 8]);
            f32x4 acc = (f32x4){0.f, 0.f, 0.f, 0.f};
            acc = __builtin_amdgcn_mfma_f32_16x16x32_bf16(qfrag[0], kf0, acc, 0, 0, 0);
            acc = __builtin_amdgcn_mfma_f32_16x16x32_bf16(qfrag[1], kf1, acc, 0, 0, 0);
#pragma unroll
            for (int r = 0; r < 4; r++) acc[r] *= 0.125f;
            s[sub] = acc;
        }

        if (kt == qt) {
#pragma unroll
            for (int sub = 0; sub < 4; sub++)
#pragma unroll
                for (int r = 0; r < 4; r++) {
                    const int kglob = kt0 + sub * 16 + col;
                    const int qglob = Q0 + w * 16 + quad * 4 + r;
                    if (kglob > qglob) s[sub][r] = -INFINITY;
                }
        }

        float mnew[4], al[4];
#pragma unroll
        for (int r = 0; r < 4; r++) {
            float t0 = fmaxf(fmaxf(s[0][r], s[1][r]), fmaxf(s[2][r], s[3][r]));
            t0 = fmaxf(t0, __shfl_xor(t0, 1));
            t0 = fmaxf(t0, __shfl_xor(t0, 2));
            t0 = fmaxf(t0, __shfl_xor(t0, 4));
            t0 = fmaxf(t0, __shfl_xor(t0, 8));
            mnew[r] = fmaxf(m_i[r], t0);
            al[r]   = __expf(m_i[r] - mnew[r]);
            m_i[r]  = mnew[r];
        }
#pragma unroll
        for (int sub = 0; sub < 4; sub++)
#pragma unroll
            for (int r = 0; r < 4; r++)
                s[sub][r] = __expf(s[sub][r] - mnew[r]);
#pragma unroll
        for (int r = 0; r < 4; r++) {
            float t0 = s[0][r] + s[1][r] + s[2][r] + s[3][r];
            t0 += __shfl_xor(t0, 1);
            t0 += __shfl_xor(t0, 2);
            t0 += __shfl_xor(t0, 4);
            t0 += __shfl_xor(t0, 8);
            l_i[r] = l_i[r] * al[r] + t0;
        }
#pragma unroll
        for (int d = 0; d < 4; d++)
#pragma unroll
            for (int r = 0; r < 4; r++)
                Oacc[d][r] *= al[r];

#pragma unroll
        for (int sub = 0; sub < 4; sub++)
#pragma unroll
            for (int r = 0; r < 4; r++)
                Pl[w][quad * 4 + r][sub * 16 + col] = f2b(s[sub][r]);
        __syncthreads();

#pragma unroll
        for (int dsub = 0; dsub < 4; dsub++) {
#pragma unroll
            for (int c = 0; c < 2; c++) {
                short8 pf = *reinterpret_cast<const short8*>(&Pl[w][col][c * 32 + quad * 8]);
                short8 vf = *reinterpret_cast<const short8*>(&Vt[dsub * 16 + col][c * 32 + quad * 8]);
                Oacc[dsub] = __builtin_amdgcn_mfma_f32_16x16x32_bf16(pf, vf, Oacc[dsub], 0, 0, 0);
            }
        }
    }

    float inv[4];
#pragma unroll
    for (int r = 0; r < 4; r++) inv[r] = 1.0f / l_i[r];
#pragma unroll
    for (int dsub = 0; dsub < 4; dsub++)
#pragma unroll
        for (int r = 0; r < 4; r++) {
            const int qglob = Q0 + w * 16 + quad * 4 + r;
            out[(size_t)(b * T + qglob) * C + h * 64 + dsub * 16 + col] =
                f2b(Oacc[dsub][r] * inv[r]);
        }
}

// ---------- launcher ----------
extern "C" void kernel_launch(void* const* d_in, const int* in_sizes, int n_in,
                              void* d_out, int out_size, void* d_ws, size_t ws_size,
                              hipStream_t stream)
{
    constexpr int B = 4, T = 2048, C = 1024;
    constexpr int M = B * T;          // 8192
    const float* x      = (const float*)d_in[0];
    const float* W_attn = (const float*)d_in[1];
    const float* b_attn = (const float*)d_in[2];
    const float* W_proj = (const float*)d_in[3];
    const float* b_proj = (const float*)d_in[4];
    float* out = (float*)d_out;

    // workspace layout (75.5 MB): qkv | {xb / attn_o aliased} | Wt_attn | Wt_proj
    char* p = (char*)d_ws;
    u16* qkv     = (u16*)p;                 p += (size_t)M * 3 * C * sizeof(u16);  // 50.3 MB
    u16* xb      = (u16*)p;                                                        // aliased
    u16* attn_o  = (u16*)p;                 p += (size_t)M * C * sizeof(u16);      // 16.8 MB
    u16* Wt_attn = (u16*)p;                 p += (size_t)3 * C * C * sizeof(u16);  // 6.3 MB
    u16* Wt_proj = (u16*)p;

    // prep: casts + weight transposes
    cast_bf16<<<dim3(M * C / (256 * 8)), 256, 0, stream>>>(x, xb, M * C);
    transpose_cast<<<dim3(3 * C / 32, C / 32), 256, 0, stream>>>(W_attn, Wt_attn, C, 3 * C);
    transpose_cast<<<dim3(C / 32, C / 32), 256, 0, stream>>>(W_proj, Wt_proj, C, C);

    // 1) qkv = xb @ Wt_attn^T + b_attn   (bf16 MFMA, bf16 out)
    gemm_mfma<u16><<<dim3(3 * C / 128, M / 128), 256, 0, stream>>>(
        xb, Wt_attn, b_attn, qkv, M, 3 * C, C);

    // 2) causal flash attention (bf16 MFMA, bf16 out)
    attn_flash<<<dim3(T / 64, B * 16), 256, 0, stream>>>(qkv, attn_o);

    // 3) out = attn_o @ Wt_proj^T + b_proj   (bf16 MFMA, fp32 out)
    gemm_mfma<float><<<dim3(C / 128, M / 128), 256, 0, stream>>>(
        attn_o, Wt_proj, b_proj, out, M, C, C);
}

// Round 6
// 407.979 us; speedup vs baseline: 13.9891x; 1.1370x over previous
//
#include <hip/hip_runtime.h>
#include <hip/hip_bf16.h>
#include <stdint.h>

typedef unsigned short u16;
typedef unsigned int   u32;

using short8 = __attribute__((ext_vector_type(8))) short;
using f32x4  = __attribute__((ext_vector_type(4))) float;

// ---------- bf16 helpers (raw-bit, RNE store) ----------
__device__ __forceinline__ float b2f(u32 u) {
    union { u32 i; float f; } v;
    v.i = u << 16;
    return v.f;
}
__device__ __forceinline__ u16 f2b(float f) {
    union { float f; u32 i; } v; v.f = f;
    u32 x = v.i;
    x += 0x7fffu + ((x >> 16) & 1u);   // round-to-nearest-even
    return (u16)(x >> 16);
}

// ---------- async global->LDS, 16B per lane ----------
__device__ __forceinline__ void gll16(const u16* g, u16* l) {
    __builtin_amdgcn_global_load_lds(
        (const __attribute__((address_space(1))) void*)g,
        (__attribute__((address_space(3))) void*)l, 16, 0, 0);
}

// ---------- prep: fp32 -> bf16 elementwise (8 elems/thread) ----------
__global__ __launch_bounds__(256)
void cast_bf16(const float* __restrict__ in, u16* __restrict__ out, int n)
{
    const int i = (blockIdx.x * 256 + threadIdx.x) * 8;
    if (i >= n) return;
    const float4 a = *reinterpret_cast<const float4*>(in + i);
    const float4 b = *reinterpret_cast<const float4*>(in + i + 4);
    u32 p0 = (u32)f2b(a.x) | ((u32)f2b(a.y) << 16);
    u32 p1 = (u32)f2b(a.z) | ((u32)f2b(a.w) << 16);
    u32 p2 = (u32)f2b(b.x) | ((u32)f2b(b.y) << 16);
    u32 p3 = (u32)f2b(b.z) | ((u32)f2b(b.w) << 16);
    *reinterpret_cast<uint4*>(out + i) = make_uint4(p0, p1, p2, p3);
}

// ---------- prep: W[R,Ncols] fp32 -> Wt[Ncols,R] bf16 (32x32 LDS tiles) ----------
__global__ __launch_bounds__(256)
void transpose_cast(const float* __restrict__ W, u16* __restrict__ Wt, int R, int Ncols)
{
    __shared__ float t[32][33];
    const int c0 = blockIdx.x * 32, r0 = blockIdx.y * 32;
    const int lx = threadIdx.x & 31, ly = threadIdx.x >> 5;   // 32 x 8
#pragma unroll
    for (int i = 0; i < 4; i++) {
        const int r = ly + i * 8;
        t[r][lx] = W[(size_t)(r0 + r) * Ncols + c0 + lx];
    }
    __syncthreads();
#pragma unroll
    for (int i = 0; i < 4; i++) {
        const int c = ly + i * 8;
        Wt[(size_t)(c0 + c) * R + r0 + lx] = f2b(t[lx][c]);
    }
}

// ---------- MFMA GEMM: C[M,N] = A[M,K] @ Bt[N,K]^T + bias[N] ----------
// A, Bt bf16; bias fp32; C = OT. 128x128 tile, BK=32, 4 waves, 4x4 acc. m97 structure.
template<typename OT>
__global__ __launch_bounds__(256)
void gemm_mfma(const u16* __restrict__ A, const u16* __restrict__ Bt,
               const float* __restrict__ bias, OT* __restrict__ C,
               int M, int N, int K)
{
    __shared__ u16 As[128 * 32];   // [row][k], row stride 32
    __shared__ u16 Bs[128 * 32];   // [col][k]

    const int tid  = threadIdx.x;
    const int w    = tid >> 6;
    const int lane = tid & 63;
    const int quad = lane >> 4;
    const int c16  = lane & 15;
    const int wr   = w >> 1, wc = w & 1;

    const int m0 = blockIdx.y * 128;
    const int n0 = blockIdx.x * 128;

    const int srow = w * 32 + (lane >> 2);
    const int skc  = (lane & 3) * 8;
    const u16* gA = A  + (size_t)(m0 + srow) * K + skc;
    const u16* gB = Bt + (size_t)(n0 + srow) * K + skc;
    u16* lA = As + w * 32 * 32 + lane * 8;
    u16* lB = Bs + w * 32 * 32 + lane * 8;

    f32x4 acc[4][4];
#pragma unroll
    for (int i = 0; i < 4; i++)
#pragma unroll
        for (int j = 0; j < 4; j++) acc[i][j] = (f32x4){0.f, 0.f, 0.f, 0.f};

    for (int k0 = 0; k0 < K; k0 += 32) {
        __syncthreads();
        gll16(gA + k0,                  lA);
        gll16(gA + k0 + 16 * (size_t)K, lA + 16 * 32);
        gll16(gB + k0,                  lB);
        gll16(gB + k0 + 16 * (size_t)K, lB + 16 * 32);
        __syncthreads();

        short8 af[4], bf[4];
#pragma unroll
        for (int i = 0; i < 4; i++)
            af[i] = *reinterpret_cast<const short8*>(&As[(wr * 64 + i * 16 + c16) * 32 + quad * 8]);
#pragma unroll
        for (int j = 0; j < 4; j++)
            bf[j] = *reinterpret_cast<const short8*>(&Bs[(wc * 64 + j * 16 + c16) * 32 + quad * 8]);
#pragma unroll
        for (int i = 0; i < 4; i++)
#pragma unroll
            for (int j = 0; j < 4; j++)
                acc[i][j] = __builtin_amdgcn_mfma_f32_16x16x32_bf16(af[i], bf[j], acc[i][j], 0, 0, 0);
    }

#pragma unroll
    for (int i = 0; i < 4; i++)
#pragma unroll
        for (int j = 0; j < 4; j++) {
            const int colg = n0 + wc * 64 + j * 16 + c16;
            const float bv = bias[colg];
#pragma unroll
            for (int r = 0; r < 4; r++) {
                const int rowg = m0 + wr * 64 + i * 16 + quad * 4 + r;
                const float v = acc[i][j][r] + bv;
                if constexpr (sizeof(OT) == 2)
                    ((u16*)C)[(size_t)rowg * N + colg] = f2b(v);
                else
                    ((float*)C)[(size_t)rowg * N + colg] = v;
            }
        }
}

// ---------- Flash attention, S^T-register variant (bf16 MFMA 16x16x32), causal ----------
// S^T = K·Q^T lands with row=key, col=q; P A-frags built by shuffles (no LDS roundtrip).
__global__ __launch_bounds__(256)
void attn_flash(const u16* __restrict__ qkv, u16* __restrict__ out)
{
    constexpr int T = 2048, C = 1024, C3 = 3072;
    constexpr int LDP = 72;

    __shared__ u16 Ks[64][LDP];       // K-tile row-major [key][d]
    __shared__ u16 Vt[64][LDP];       // V-tile transposed [d][key]

    const int tid  = threadIdx.x;
    const int w    = tid >> 6;
    const int lane = tid & 63;
    const int quad = lane >> 4;
    const int c16  = lane & 15;

    const int qt = (T / 64 - 1) - blockIdx.x;   // reversed: heavy blocks first
    const int bh = blockIdx.y;
    const int h  = bh & 15;
    const int b  = bh >> 4;
    const int Q0 = qt * 64;
    const int qglob = Q0 + w * 16 + c16;        // this lane's q-row (as S^T column)

    const size_t rowQ = (size_t)(b * T + qglob) * C3 + h * 64;
    short8 qfrag[2];
    qfrag[0] = *reinterpret_cast<const short8*>(qkv + rowQ + 0 * 32 + quad * 8);
    qfrag[1] = *reinterpret_cast<const short8*>(qkv + rowQ + 1 * 32 + quad * 8);

    f32x4 Oacc[4];
#pragma unroll
    for (int d = 0; d < 4; d++) Oacc[d] = (f32x4){0.f, 0.f, 0.f, 0.f};
    float m_i = -INFINITY, l_i = 0.f;   // per q = c16 (replicated across quads)

    for (int kt = 0; kt <= qt; kt++) {
        const int kt0 = kt * 64;
        __syncthreads();   // previous tile's LDS reads complete

        // ---- stage K tile: thread t -> key t>>2, d (t&3)*16..+15 (2x16B)
        {
            const int r = tid >> 2, cg = (tid & 3) * 16;
            const uint4* gp = reinterpret_cast<const uint4*>(
                qkv + (size_t)(b * T + kt0 + r) * C3 + C + h * 64 + cg);
            *reinterpret_cast<uint4*>(&Ks[r][cg])     = gp[0];
            *reinterpret_cast<uint4*>(&Ks[r][cg + 8]) = gp[1];
        }
        // ---- stage V transposed: kp = t&31 (conflict-free banks), dg = (t>>5)*8
        {
            const int kp = tid & 31, dg = (tid >> 5) * 8;
            const u16* g0 = qkv + (size_t)(b * T + kt0 + 2 * kp) * C3 + 2 * C + h * 64 + dg;
            uint4 v0 = *reinterpret_cast<const uint4*>(g0);
            uint4 v1 = *reinterpret_cast<const uint4*>(g0 + C3);
            const u16* p0 = reinterpret_cast<const u16*>(&v0);
            const u16* p1 = reinterpret_cast<const u16*>(&v1);
#pragma unroll
            for (int i = 0; i < 8; i++)
                *reinterpret_cast<u32*>(&Vt[dg + i][2 * kp]) =
                    (u32)p0[i] | ((u32)p1[i] << 16);
        }
        __syncthreads();

        // ---- S^T = K Q^T: row = key = sub*16 + quad*4 + r, col = q = c16
        f32x4 s[4];
#pragma unroll
        for (int sub = 0; sub < 4; sub++) {
            short8 kf0 = *reinterpret_cast<const short8*>(&Ks[sub * 16 + c16][0 * 32 + quad * 8]);
            short8 kf1 = *reinterpret_cast<const short8*>(&Ks[sub * 16 + c16][1 * 32 + quad * 8]);
            f32x4 acc = (f32x4){0.f, 0.f, 0.f, 0.f};
            acc = __builtin_amdgcn_mfma_f32_16x16x32_bf16(kf0, qfrag[0], acc, 0, 0, 0);
            acc = __builtin_amdgcn_mfma_f32_16x16x32_bf16(kf1, qfrag[1], acc, 0, 0, 0);
#pragma unroll
            for (int r = 0; r < 4; r++) acc[r] *= 0.125f;   // 1/sqrt(64)
            s[sub] = acc;
        }

        // ---- causal mask (diagonal tile only)
        if (kt == qt) {
#pragma unroll
            for (int sub = 0; sub < 4; sub++)
#pragma unroll
                for (int r = 0; r < 4; r++)
                    if (kt0 + sub * 16 + quad * 4 + r > qglob) s[sub][r] = -INFINITY;
        }

        // ---- online softmax over keys (local 16 values + cross-quad shfl_xor)
        float mloc = -INFINITY;
#pragma unroll
        for (int sub = 0; sub < 4; sub++)
#pragma unroll
            for (int r = 0; r < 4; r++) mloc = fmaxf(mloc, s[sub][r]);
        mloc = fmaxf(mloc, __shfl_xor(mloc, 16));
        mloc = fmaxf(mloc, __shfl_xor(mloc, 32));
        const float mnew = fmaxf(m_i, mloc);
        const float al   = __expf(m_i - mnew);
        m_i = mnew;

        float ls = 0.f;
#pragma unroll
        for (int sub = 0; sub < 4; sub++)
#pragma unroll
            for (int r = 0; r < 4; r++) {
                s[sub][r] = __expf(s[sub][r] - mnew);
                ls += s[sub][r];
            }
        ls += __shfl_xor(ls, 16);
        ls += __shfl_xor(ls, 32);
        l_i = l_i * al + ls;

        // ---- rescale O (rows q = quad*4 + r need al of that q, from lanes 0..15)
#pragma unroll
        for (int r = 0; r < 4; r++) {
            const float alr = __shfl(al, quad * 4 + r);
#pragma unroll
            for (int d = 0; d < 4; d++) Oacc[d][r] *= alr;
        }

        // ---- build P A-frags from S^T registers (no LDS roundtrip)
        // af elem j of chunk c = P[q=c16][key = c*32 + quad*8 + j]
        short8 pf[2];
#pragma unroll
        for (int c = 0; c < 2; c++) {
#pragma unroll
            for (int j = 0; j < 8; j++) {
                const int src = ((quad & 1) * 2 + (j >> 2)) * 16 + c16;
                const float vlo = __shfl(s[2 * c][j & 3], src);
                const float vhi = __shfl(s[2 * c + 1][j & 3], src);
                pf[c][j] = (short)f2b(quad >= 2 ? vhi : vlo);
            }
        }

        // ---- O += P V
#pragma unroll
        for (int dsub = 0; dsub < 4; dsub++) {
#pragma unroll
            for (int c = 0; c < 2; c++) {
                short8 vf = *reinterpret_cast<const short8*>(&Vt[dsub * 16 + c16][c * 32 + quad * 8]);
                Oacc[dsub] = __builtin_amdgcn_mfma_f32_16x16x32_bf16(pf[c], vf, Oacc[dsub], 0, 0, 0);
            }
        }
    }

    // ---- epilogue: O rows are q = quad*4 + r, cols d = dsub*16 + c16
    const float inv = 1.0f / l_i;
#pragma unroll
    for (int r = 0; r < 4; r++) {
        const float invr = __shfl(inv, quad * 4 + r);
        const int qrow = Q0 + w * 16 + quad * 4 + r;
#pragma unroll
        for (int dsub = 0; dsub < 4; dsub++)
            out[(size_t)(b * T + qrow) * C + h * 64 + dsub * 16 + c16] =
                f2b(Oacc[dsub][r] * invr);
    }
}

// ---------- launcher ----------
extern "C" void kernel_launch(void* const* d_in, const int* in_sizes, int n_in,
                              void* d_out, int out_size, void* d_ws, size_t ws_size,
                              hipStream_t stream)
{
    constexpr int B = 4, T = 2048, C = 1024;
    constexpr int M = B * T;          // 8192
    const float* x      = (const float*)d_in[0];
    const float* W_attn = (const float*)d_in[1];
    const float* b_attn = (const float*)d_in[2];
    const float* W_proj = (const float*)d_in[3];
    const float* b_proj = (const float*)d_in[4];
    float* out = (float*)d_out;

    // workspace layout: qkv | {xb / attn_o aliased} | Wt_attn | Wt_proj
    char* p = (char*)d_ws;
    u16* qkv     = (u16*)p;                 p += (size_t)M * 3 * C * sizeof(u16);
    u16* xb      = (u16*)p;
    u16* attn_o  = (u16*)p;                 p += (size_t)M * C * sizeof(u16);
    u16* Wt_attn = (u16*)p;                 p += (size_t)3 * C * C * sizeof(u16);
    u16* Wt_proj = (u16*)p;

    cast_bf16<<<dim3(M * C / (256 * 8)), 256, 0, stream>>>(x, xb, M * C);
    transpose_cast<<<dim3(3 * C / 32, C / 32), 256, 0, stream>>>(W_attn, Wt_attn, C, 3 * C);
    transpose_cast<<<dim3(C / 32, C / 32), 256, 0, stream>>>(W_proj, Wt_proj, C, C);

    gemm_mfma<u16><<<dim3(3 * C / 128, M / 128), 256, 0, stream>>>(
        xb, Wt_attn, b_attn, qkv, M, 3 * C, C);

    attn_flash<<<dim3(T / 64, B * 16), 256, 0, stream>>>(qkv, attn_o);

    gemm_mfma<float><<<dim3(C / 128, M / 128), 256, 0, stream>>>(
        attn_o, Wt_proj, b_proj, out, M, C, C);
}

// Round 7
// 407.285 us; speedup vs baseline: 14.0130x; 1.0017x over previous
//
#include <hip/hip_runtime.h>
#include <hip/hip_bf16.h>
#include <stdint.h>

typedef unsigned short u16;
typedef unsigned int   u32;

using short8 = __attribute__((ext_vector_type(8))) short;
using f32x4  = __attribute__((ext_vector_type(4))) float;

// ---------- bf16 helpers (raw-bit, RNE store) ----------
__device__ __forceinline__ float b2f(u32 u) {
    union { u32 i; float f; } v;
    v.i = u << 16;
    return v.f;
}
__device__ __forceinline__ u16 f2b(float f) {
    union { float f; u32 i; } v; v.f = f;
    u32 x = v.i;
    x += 0x7fffu + ((x >> 16) & 1u);   // round-to-nearest-even
    return (u16)(x >> 16);
}

// ---------- async global->LDS, 16B per lane ----------
__device__ __forceinline__ void gll16(const u16* g, u16* l) {
    __builtin_amdgcn_global_load_lds(
        (const __attribute__((address_space(1))) void*)g,
        (__attribute__((address_space(3))) void*)l, 16, 0, 0);
}

// ---------- prep: fp32 -> bf16 elementwise (8 elems/thread) ----------
__global__ __launch_bounds__(256)
void cast_bf16(const float* __restrict__ in, u16* __restrict__ out, int n)
{
    const int i = (blockIdx.x * 256 + threadIdx.x) * 8;
    if (i >= n) return;
    const float4 a = *reinterpret_cast<const float4*>(in + i);
    const float4 b = *reinterpret_cast<const float4*>(in + i + 4);
    u32 p0 = (u32)f2b(a.x) | ((u32)f2b(a.y) << 16);
    u32 p1 = (u32)f2b(a.z) | ((u32)f2b(a.w) << 16);
    u32 p2 = (u32)f2b(b.x) | ((u32)f2b(b.y) << 16);
    u32 p3 = (u32)f2b(b.z) | ((u32)f2b(b.w) << 16);
    *reinterpret_cast<uint4*>(out + i) = make_uint4(p0, p1, p2, p3);
}

// ---------- prep: W[R,Ncols] fp32 -> Wt[Ncols,R] bf16 (32x32 LDS tiles) ----------
__global__ __launch_bounds__(256)
void transpose_cast(const float* __restrict__ W, u16* __restrict__ Wt, int R, int Ncols)
{
    __shared__ float t[32][33];
    const int c0 = blockIdx.x * 32, r0 = blockIdx.y * 32;
    const int lx = threadIdx.x & 31, ly = threadIdx.x >> 5;   // 32 x 8
#pragma unroll
    for (int i = 0; i < 4; i++) {
        const int r = ly + i * 8;
        t[r][lx] = W[(size_t)(r0 + r) * Ncols + c0 + lx];
    }
    __syncthreads();
#pragma unroll
    for (int i = 0; i < 4; i++) {
        const int c = ly + i * 8;
        Wt[(size_t)(c0 + c) * R + r0 + lx] = f2b(t[lx][c]);
    }
}

// ---------- MFMA GEMM: C[M,N] = A[M,K] @ Bt[N,K]^T + bias[N] ----------
// A, Bt bf16; bias fp32; C = OT. 128x128 tile, BK=32, 4 waves, 4x4 acc. m97 structure.
template<typename OT>
__global__ __launch_bounds__(256)
void gemm_mfma(const u16* __restrict__ A, const u16* __restrict__ Bt,
               const float* __restrict__ bias, OT* __restrict__ C,
               int M, int N, int K)
{
    __shared__ u16 As[128 * 32];   // [row][k], row stride 32
    __shared__ u16 Bs[128 * 32];   // [col][k]

    const int tid  = threadIdx.x;
    const int w    = tid >> 6;
    const int lane = tid & 63;
    const int quad = lane >> 4;
    const int c16  = lane & 15;
    const int wr   = w >> 1, wc = w & 1;

    const int m0 = blockIdx.y * 128;
    const int n0 = blockIdx.x * 128;

    const int srow = w * 32 + (lane >> 2);
    const int skc  = (lane & 3) * 8;
    const u16* gA = A  + (size_t)(m0 + srow) * K + skc;
    const u16* gB = Bt + (size_t)(n0 + srow) * K + skc;
    u16* lA = As + w * 32 * 32 + lane * 8;
    u16* lB = Bs + w * 32 * 32 + lane * 8;

    f32x4 acc[4][4];
#pragma unroll
    for (int i = 0; i < 4; i++)
#pragma unroll
        for (int j = 0; j < 4; j++) acc[i][j] = (f32x4){0.f, 0.f, 0.f, 0.f};

    for (int k0 = 0; k0 < K; k0 += 32) {
        __syncthreads();
        gll16(gA + k0,                  lA);
        gll16(gA + k0 + 16 * (size_t)K, lA + 16 * 32);
        gll16(gB + k0,                  lB);
        gll16(gB + k0 + 16 * (size_t)K, lB + 16 * 32);
        __syncthreads();

        short8 af[4], bf[4];
#pragma unroll
        for (int i = 0; i < 4; i++)
            af[i] = *reinterpret_cast<const short8*>(&As[(wr * 64 + i * 16 + c16) * 32 + quad * 8]);
#pragma unroll
        for (int j = 0; j < 4; j++)
            bf[j] = *reinterpret_cast<const short8*>(&Bs[(wc * 64 + j * 16 + c16) * 32 + quad * 8]);
#pragma unroll
        for (int i = 0; i < 4; i++)
#pragma unroll
            for (int j = 0; j < 4; j++)
                acc[i][j] = __builtin_amdgcn_mfma_f32_16x16x32_bf16(af[i], bf[j], acc[i][j], 0, 0, 0);
    }

#pragma unroll
    for (int i = 0; i < 4; i++)
#pragma unroll
        for (int j = 0; j < 4; j++) {
            const int colg = n0 + wc * 64 + j * 16 + c16;
            const float bv = bias[colg];
#pragma unroll
            for (int r = 0; r < 4; r++) {
                const int rowg = m0 + wr * 64 + i * 16 + quad * 4 + r;
                const float v = acc[i][j][r] + bv;
                if constexpr (sizeof(OT) == 2)
                    ((u16*)C)[(size_t)rowg * N + colg] = f2b(v);
                else
                    ((float*)C)[(size_t)rowg * N + colg] = v;
            }
        }
}

// ---------- Flash attention, S^T-register + double-buffered pipeline, causal ----------
// S^T = K·Q^T (row=key, col=q); P A-frags via shuffles; LDS double-buffer,
// register prefetch of next K/V tile, ONE barrier per k-tile.
__global__ __launch_bounds__(256)
void attn_flash(const u16* __restrict__ qkv, u16* __restrict__ out)
{
    constexpr int T = 2048, C = 1024, C3 = 3072;
    constexpr int LDP = 72;

    __shared__ u16 Ks[2][64][LDP];    // K-tile row-major [key][d]
    __shared__ u16 Vt[2][64][LDP];    // V-tile transposed [d][key]

    const int tid  = threadIdx.x;
    const int w    = tid >> 6;
    const int lane = tid & 63;
    const int quad = lane >> 4;
    const int c16  = lane & 15;

    const int qt = (T / 64 - 1) - blockIdx.x;   // reversed: heavy blocks first
    const int bh = blockIdx.y;
    const int h  = bh & 15;
    const int b  = bh >> 4;
    const int Q0 = qt * 64;
    const int qglob = Q0 + w * 16 + c16;        // this lane's q-row (as S^T column)

    // Q fragments, pre-scaled by 1/sqrt(64) = 0.125 (exact in bf16)
    const size_t rowQ = (size_t)(b * T + qglob) * C3 + h * 64;
    short8 qfrag[2];
#pragma unroll
    for (int c = 0; c < 2; c++) {
        short8 raw = *reinterpret_cast<const short8*>(qkv + rowQ + c * 32 + quad * 8);
#pragma unroll
        for (int j = 0; j < 8; j++)
            qfrag[c][j] = (short)f2b(b2f((u16)raw[j]) * 0.125f);
    }

    // staging coordinates
    const int kr  = tid >> 2, kc = (tid & 3) * 16;   // K: row kr, cols kc..kc+15
    const int vkp = tid & 31, vdg = (tid >> 5) * 8;  // V: keys 2vkp,2vkp+1, d vdg..+7

    uint4 ka, kb, va, vb;                            // prefetch registers
    const u16* baseK = qkv + (size_t)(b * T + kr) * C3 + C + h * 64 + kc;
    const u16* baseV = qkv + (size_t)(b * T + 2 * vkp) * C3 + 2 * C + h * 64 + vdg;

    auto load_regs = [&](int kt0) {
        const uint4* gp = reinterpret_cast<const uint4*>(baseK + (size_t)kt0 * C3);
        ka = gp[0];
        kb = gp[1];
        const u16* g0 = baseV + (size_t)kt0 * C3;
        va = *reinterpret_cast<const uint4*>(g0);
        vb = *reinterpret_cast<const uint4*>(g0 + C3);
    };
    auto write_lds = [&](int bi) {
        *reinterpret_cast<uint4*>(&Ks[bi][kr][kc])     = ka;
        *reinterpret_cast<uint4*>(&Ks[bi][kr][kc + 8]) = kb;
        const u16* p0 = reinterpret_cast<const u16*>(&va);
        const u16* p1 = reinterpret_cast<const u16*>(&vb);
#pragma unroll
        for (int i = 0; i < 8; i++)
            *reinterpret_cast<u32*>(&Vt[bi][vdg + i][2 * vkp]) =
                (u32)p0[i] | ((u32)p1[i] << 16);
    };

    f32x4 Oacc[4];
#pragma unroll
    for (int d = 0; d < 4; d++) Oacc[d] = (f32x4){0.f, 0.f, 0.f, 0.f};
    float m_i = -INFINITY, l_i = 0.f;   // per q = c16 (replicated across quads)

    // prologue: tile 0 staged
    load_regs(0);
    write_lds(0);
    __syncthreads();

    for (int kt = 0; kt <= qt; kt++) {
        const int cur = kt & 1;
        const int kt0 = kt * 64;

        if (kt < qt) load_regs(kt0 + 64);   // async prefetch next tile

        // ---- S^T = K Q^T: row = key = sub*16 + quad*4 + r, col = q = c16
        f32x4 s[4];
#pragma unroll
        for (int sub = 0; sub < 4; sub++) {
            short8 kf0 = *reinterpret_cast<const short8*>(&Ks[cur][sub * 16 + c16][0 * 32 + quad * 8]);
            short8 kf1 = *reinterpret_cast<const short8*>(&Ks[cur][sub * 16 + c16][1 * 32 + quad * 8]);
            f32x4 acc = (f32x4){0.f, 0.f, 0.f, 0.f};
            acc = __builtin_amdgcn_mfma_f32_16x16x32_bf16(kf0, qfrag[0], acc, 0, 0, 0);
            acc = __builtin_amdgcn_mfma_f32_16x16x32_bf16(kf1, qfrag[1], acc, 0, 0, 0);
            s[sub] = acc;
        }

        // ---- causal mask (diagonal tile only)
        if (kt == qt) {
#pragma unroll
            for (int sub = 0; sub < 4; sub++)
#pragma unroll
                for (int r = 0; r < 4; r++)
                    if (kt0 + sub * 16 + quad * 4 + r > qglob) s[sub][r] = -INFINITY;
        }

        // ---- online softmax over keys (16 local + cross-quad shfl_xor)
        float mloc = -INFINITY;
#pragma unroll
        for (int sub = 0; sub < 4; sub++)
#pragma unroll
            for (int r = 0; r < 4; r++) mloc = fmaxf(mloc, s[sub][r]);
        mloc = fmaxf(mloc, __shfl_xor(mloc, 16));
        mloc = fmaxf(mloc, __shfl_xor(mloc, 32));
        const float mnew = fmaxf(m_i, mloc);
        const float al   = __expf(m_i - mnew);
        m_i = mnew;

        float ls = 0.f;
#pragma unroll
        for (int sub = 0; sub < 4; sub++)
#pragma unroll
            for (int r = 0; r < 4; r++) {
                s[sub][r] = __expf(s[sub][r] - mnew);
                ls += s[sub][r];
            }
        ls += __shfl_xor(ls, 16);
        ls += __shfl_xor(ls, 32);
        l_i = l_i * al + ls;

        // ---- rescale O (row q = quad*4 + r takes al of that q from lanes 0..15)
#pragma unroll
        for (int r = 0; r < 4; r++) {
            const float alr = __shfl(al, quad * 4 + r);
#pragma unroll
            for (int d = 0; d < 4; d++) Oacc[d][r] *= alr;
        }

        // ---- build P A-frags from S^T registers
        short8 pf[2];
#pragma unroll
        for (int c = 0; c < 2; c++) {
#pragma unroll
            for (int j = 0; j < 8; j++) {
                const int src = ((quad & 1) * 2 + (j >> 2)) * 16 + c16;
                const float vlo = __shfl(s[2 * c][j & 3], src);
                const float vhi = __shfl(s[2 * c + 1][j & 3], src);
                pf[c][j] = (short)f2b(quad >= 2 ? vhi : vlo);
            }
        }

        // ---- O += P V
#pragma unroll
        for (int dsub = 0; dsub < 4; dsub++) {
#pragma unroll
            for (int c = 0; c < 2; c++) {
                short8 vf = *reinterpret_cast<const short8*>(&Vt[cur][dsub * 16 + c16][c * 32 + quad * 8]);
                Oacc[dsub] = __builtin_amdgcn_mfma_f32_16x16x32_bf16(pf[c], vf, Oacc[dsub], 0, 0, 0);
            }
        }

        if (kt < qt) write_lds(cur ^ 1);    // drain prefetch into other buffer
        __syncthreads();                    // one barrier per tile
    }

    // ---- epilogue: O rows are q = quad*4 + r, cols d = dsub*16 + c16
    const float inv = 1.0f / l_i;
#pragma unroll
    for (int r = 0; r < 4; r++) {
        const float invr = __shfl(inv, quad * 4 + r);
        const int qrow = Q0 + w * 16 + quad * 4 + r;
#pragma unroll
        for (int dsub = 0; dsub < 4; dsub++)
            out[(size_t)(b * T + qrow) * C + h * 64 + dsub * 16 + c16] =
                f2b(Oacc[dsub][r] * invr);
    }
}

// ---------- launcher ----------
extern "C" void kernel_launch(void* const* d_in, const int* in_sizes, int n_in,
                              void* d_out, int out_size, void* d_ws, size_t ws_size,
                              hipStream_t stream)
{
    constexpr int B = 4, T = 2048, C = 1024;
    constexpr int M = B * T;          // 8192
    const float* x      = (const float*)d_in[0];
    const float* W_attn = (const float*)d_in[1];
    const float* b_attn = (const float*)d_in[2];
    const float* W_proj = (const float*)d_in[3];
    const float* b_proj = (const float*)d_in[4];
    float* out = (float*)d_out;

    // workspace layout: qkv | {xb / attn_o aliased} | Wt_attn | Wt_proj
    char* p = (char*)d_ws;
    u16* qkv     = (u16*)p;                 p += (size_t)M * 3 * C * sizeof(u16);
    u16* xb      = (u16*)p;
    u16* attn_o  = (u16*)p;                 p += (size_t)M * C * sizeof(u16);
    u16* Wt_attn = (u16*)p;                 p += (size_t)3 * C * C * sizeof(u16);
    u16* Wt_proj = (u16*)p;

    cast_bf16<<<dim3(M * C / (256 * 8)), 256, 0, stream>>>(x, xb, M * C);
    transpose_cast<<<dim3(3 * C / 32, C / 32), 256, 0, stream>>>(W_attn, Wt_attn, C, 3 * C);
    transpose_cast<<<dim3(C / 32, C / 32), 256, 0, stream>>>(W_proj, Wt_proj, C, C);

    gemm_mfma<u16><<<dim3(3 * C / 128, M / 128), 256, 0, stream>>>(
        xb, Wt_attn, b_attn, qkv, M, 3 * C, C);

    attn_flash<<<dim3(T / 64, B * 16), 256, 0, stream>>>(qkv, attn_o);

    gemm_mfma<float><<<dim3(C / 128, M / 128), 256, 0, stream>>>(
        attn_o, Wt_proj, b_proj, out, M, C, C);
}

// Round 8
// 327.653 us; speedup vs baseline: 17.4186x; 1.2430x over previous
//
#include <hip/hip_runtime.h>
#include <hip/hip_bf16.h>
#include <stdint.h>

typedef unsigned short u16;
typedef unsigned int   u32;

using short8 = __attribute__((ext_vector_type(8))) short;
using f32x4  = __attribute__((ext_vector_type(4))) float;

// ---------- bf16 helpers (raw-bit, RNE store) ----------
__device__ __forceinline__ float b2f(u32 u) {
    union { u32 i; float f; } v;
    v.i = u << 16;
    return v.f;
}
__device__ __forceinline__ u16 f2b(float f) {
    union { float f; u32 i; } v; v.f = f;
    u32 x = v.i;
    x += 0x7fffu + ((x >> 16) & 1u);   // round-to-nearest-even
    return (u16)(x >> 16);
}

// ---------- async global->LDS, 16B per lane ----------
__device__ __forceinline__ void gll16(const u16* g, u16* l) {
    __builtin_amdgcn_global_load_lds(
        (const __attribute__((address_space(1))) void*)g,
        (__attribute__((address_space(3))) void*)l, 16, 0, 0);
}

// ---------- prep: fp32 -> bf16 elementwise (8 elems/thread) ----------
__global__ __launch_bounds__(256)
void cast_bf16(const float* __restrict__ in, u16* __restrict__ out, int n)
{
    const int i = (blockIdx.x * 256 + threadIdx.x) * 8;
    if (i >= n) return;
    const float4 a = *reinterpret_cast<const float4*>(in + i);
    const float4 b = *reinterpret_cast<const float4*>(in + i + 4);
    u32 p0 = (u32)f2b(a.x) | ((u32)f2b(a.y) << 16);
    u32 p1 = (u32)f2b(a.z) | ((u32)f2b(a.w) << 16);
    u32 p2 = (u32)f2b(b.x) | ((u32)f2b(b.y) << 16);
    u32 p3 = (u32)f2b(b.z) | ((u32)f2b(b.w) << 16);
    *reinterpret_cast<uint4*>(out + i) = make_uint4(p0, p1, p2, p3);
}

// ---------- prep: W[R,Ncols] fp32 -> Wt[Ncols,R] bf16 (32x32 LDS tiles) ----------
__global__ __launch_bounds__(256)
void transpose_cast(const float* __restrict__ W, u16* __restrict__ Wt, int R, int Ncols)
{
    __shared__ float t[32][33];
    const int c0 = blockIdx.x * 32, r0 = blockIdx.y * 32;
    const int lx = threadIdx.x & 31, ly = threadIdx.x >> 5;   // 32 x 8
#pragma unroll
    for (int i = 0; i < 4; i++) {
        const int r = ly + i * 8;
        t[r][lx] = W[(size_t)(r0 + r) * Ncols + c0 + lx];
    }
    __syncthreads();
#pragma unroll
    for (int i = 0; i < 4; i++) {
        const int c = ly + i * 8;
        Wt[(size_t)(c0 + c) * R + r0 + lx] = f2b(t[lx][c]);
    }
}

// ---------- MFMA GEMM: C[M,N] = A[M,K] @ Bt[N,K]^T + bias[N] ----------
template<typename OT>
__global__ __launch_bounds__(256)
void gemm_mfma(const u16* __restrict__ A, const u16* __restrict__ Bt,
               const float* __restrict__ bias, OT* __restrict__ C,
               int M, int N, int K)
{
    __shared__ u16 As[128 * 32];   // [row][k], row stride 32
    __shared__ u16 Bs[128 * 32];   // [col][k]

    const int tid  = threadIdx.x;
    const int w    = tid >> 6;
    const int lane = tid & 63;
    const int quad = lane >> 4;
    const int c16  = lane & 15;
    const int wr   = w >> 1, wc = w & 1;

    const int m0 = blockIdx.y * 128;
    const int n0 = blockIdx.x * 128;

    const int srow = w * 32 + (lane >> 2);
    const int skc  = (lane & 3) * 8;
    const u16* gA = A  + (size_t)(m0 + srow) * K + skc;
    const u16* gB = Bt + (size_t)(n0 + srow) * K + skc;
    u16* lA = As + w * 32 * 32 + lane * 8;
    u16* lB = Bs + w * 32 * 32 + lane * 8;

    f32x4 acc[4][4];
#pragma unroll
    for (int i = 0; i < 4; i++)
#pragma unroll
        for (int j = 0; j < 4; j++) acc[i][j] = (f32x4){0.f, 0.f, 0.f, 0.f};

    for (int k0 = 0; k0 < K; k0 += 32) {
        __syncthreads();
        gll16(gA + k0,                  lA);
        gll16(gA + k0 + 16 * (size_t)K, lA + 16 * 32);
        gll16(gB + k0,                  lB);
        gll16(gB + k0 + 16 * (size_t)K, lB + 16 * 32);
        __syncthreads();

        short8 af[4], bf[4];
#pragma unroll
        for (int i = 0; i < 4; i++)
            af[i] = *reinterpret_cast<const short8*>(&As[(wr * 64 + i * 16 + c16) * 32 + quad * 8]);
#pragma unroll
        for (int j = 0; j < 4; j++)
            bf[j] = *reinterpret_cast<const short8*>(&Bs[(wc * 64 + j * 16 + c16) * 32 + quad * 8]);
#pragma unroll
        for (int i = 0; i < 4; i++)
#pragma unroll
            for (int j = 0; j < 4; j++)
                acc[i][j] = __builtin_amdgcn_mfma_f32_16x16x32_bf16(af[i], bf[j], acc[i][j], 0, 0, 0);
    }

#pragma unroll
    for (int i = 0; i < 4; i++)
#pragma unroll
        for (int j = 0; j < 4; j++) {
            const int colg = n0 + wc * 64 + j * 16 + c16;
            const float bv = bias[colg];
#pragma unroll
            for (int r = 0; r < 4; r++) {
                const int rowg = m0 + wr * 64 + i * 16 + quad * 4 + r;
                const float v = acc[i][j][r] + bv;
                if constexpr (sizeof(OT) == 2)
                    ((u16*)C)[(size_t)rowg * N + colg] = f2b(v);
                else
                    ((float*)C)[(size_t)rowg * N + colg] = v;
            }
        }
}

// ---------- Flash attention: paired q-tiles, S^T MFMA, LDS P-transform ----------
// Block x = 0..15 handles q-tiles {x, 31-x} (causal work sums to 33 tiles for all
// blocks -> perfectly balanced 1024-block grid, 4 blocks/CU resident).
// S^T = K.Q^T (row=key, col=q); P via per-wave LDS roundtrip (no barrier).
constexpr int ALDP = 72;   // LDS row pad (u16 units)

struct TileState {
    f32x4 O[4];
    float m, l;
    short8 qf[2];
    int qglob;
};

__device__ __forceinline__ void tile_pass(
    const u16 (*__restrict__ Ks)[ALDP], const u16 (*__restrict__ Vt)[ALDP],
    u16* __restrict__ plrow,           // per-wave Pl base: [16][ALDP]
    TileState& ts, int kt0, bool diag, int quad, int c16)
{
    // ---- S^T = K Q^T: s[sub][r] = S^T[key = kt0+sub*16+quad*4+r][q = ts.qglob]
    f32x4 s[4];
#pragma unroll
    for (int sub = 0; sub < 4; sub++) {
        short8 kf0 = *reinterpret_cast<const short8*>(&Ks[sub * 16 + c16][0 * 32 + quad * 8]);
        short8 kf1 = *reinterpret_cast<const short8*>(&Ks[sub * 16 + c16][1 * 32 + quad * 8]);
        f32x4 acc = (f32x4){0.f, 0.f, 0.f, 0.f};
        acc = __builtin_amdgcn_mfma_f32_16x16x32_bf16(kf0, ts.qf[0], acc, 0, 0, 0);
        acc = __builtin_amdgcn_mfma_f32_16x16x32_bf16(kf1, ts.qf[1], acc, 0, 0, 0);
        s[sub] = acc;
    }

    if (diag) {
#pragma unroll
        for (int sub = 0; sub < 4; sub++)
#pragma unroll
            for (int r = 0; r < 4; r++)
                if (kt0 + sub * 16 + quad * 4 + r > ts.qglob) s[sub][r] = -INFINITY;
    }

    // ---- online softmax over keys (16 local + cross-quad shfl_xor)
    float mloc = -INFINITY;
#pragma unroll
    for (int sub = 0; sub < 4; sub++)
#pragma unroll
        for (int r = 0; r < 4; r++) mloc = fmaxf(mloc, s[sub][r]);
    mloc = fmaxf(mloc, __shfl_xor(mloc, 16));
    mloc = fmaxf(mloc, __shfl_xor(mloc, 32));
    const float mnew = fmaxf(ts.m, mloc);
    const float al   = __expf(ts.m - mnew);
    ts.m = mnew;

    float ls = 0.f;
#pragma unroll
    for (int sub = 0; sub < 4; sub++)
#pragma unroll
        for (int r = 0; r < 4; r++) {
            s[sub][r] = __expf(s[sub][r] - mnew);
            ls += s[sub][r];
        }
    ls += __shfl_xor(ls, 16);
    ls += __shfl_xor(ls, 32);
    ts.l = ts.l * al + ls;

    // ---- rescale O (row q = quad*4 + r takes al of that q from lanes 0..15)
#pragma unroll
    for (int r = 0; r < 4; r++) {
        const float alr = __shfl(al, quad * 4 + r);
#pragma unroll
        for (int d = 0; d < 4; d++) ts.O[d][r] *= alr;
    }

    // ---- P: write packed rows to per-wave LDS (keys sub*16+quad*4..+3 consecutive)
#pragma unroll
    for (int sub = 0; sub < 4; sub++) {
        u32 lo = (u32)f2b(s[sub][0]) | ((u32)f2b(s[sub][1]) << 16);
        u32 hi = (u32)f2b(s[sub][2]) | ((u32)f2b(s[sub][3]) << 16);
        *reinterpret_cast<uint2*>(plrow + c16 * ALDP + sub * 16 + quad * 4) =
            make_uint2(lo, hi);
    }
    // A-layout read back (wave-local; compiler orders via lgkmcnt)
    short8 pf[2];
#pragma unroll
    for (int c = 0; c < 2; c++)
        pf[c] = *reinterpret_cast<const short8*>(plrow + c16 * ALDP + c * 32 + quad * 8);

    // ---- O += P V
#pragma unroll
    for (int dsub = 0; dsub < 4; dsub++) {
#pragma unroll
        for (int c = 0; c < 2; c++) {
            short8 vf = *reinterpret_cast<const short8*>(&Vt[dsub * 16 + c16][c * 32 + quad * 8]);
            ts.O[dsub] = __builtin_amdgcn_mfma_f32_16x16x32_bf16(pf[c], vf, ts.O[dsub], 0, 0, 0);
        }
    }
}

__global__ __launch_bounds__(256, 4)
void attn_flash(const u16* __restrict__ qkv, u16* __restrict__ out)
{
    constexpr int T = 2048, C = 1024, C3 = 3072;

    __shared__ u16 Ks[64][ALDP];      // K-tile row-major [key][d]
    __shared__ u16 Vt[64][ALDP];      // V-tile transposed [d][key]
    __shared__ u16 Pl[4][16][ALDP];   // per-wave P scratch

    const int tid  = threadIdx.x;
    const int w    = tid >> 6;
    const int lane = tid & 63;
    const int quad = lane >> 4;
    const int c16  = lane & 15;

    const int qtA = blockIdx.x;        // 0..15  (light tile)
    const int qtB = 31 - qtA;          // 16..31 (heavy tile)
    const int bh  = blockIdx.y;
    const int h   = bh & 15;
    const int b   = bh >> 4;

    TileState A, B;
    A.qglob = qtA * 64 + w * 16 + c16;
    B.qglob = qtB * 64 + w * 16 + c16;
    A.m = B.m = -INFINITY;
    A.l = B.l = 0.f;
#pragma unroll
    for (int d = 0; d < 4; d++) {
        A.O[d] = (f32x4){0.f, 0.f, 0.f, 0.f};
        B.O[d] = (f32x4){0.f, 0.f, 0.f, 0.f};
    }
    // Q fragments pre-scaled by 1/sqrt(64) = 0.125 (exact in bf16)
#pragma unroll
    for (int c = 0; c < 2; c++) {
        short8 ra = *reinterpret_cast<const short8*>(
            qkv + (size_t)(b * T + A.qglob) * C3 + h * 64 + c * 32 + quad * 8);
        short8 rb = *reinterpret_cast<const short8*>(
            qkv + (size_t)(b * T + B.qglob) * C3 + h * 64 + c * 32 + quad * 8);
#pragma unroll
        for (int j = 0; j < 8; j++) {
            A.qf[c][j] = (short)f2b(b2f((u16)ra[j]) * 0.125f);
            B.qf[c][j] = (short)f2b(b2f((u16)rb[j]) * 0.125f);
        }
    }

    // staging coordinates
    const int kr  = tid >> 2, kc = (tid & 3) * 16;   // K: row kr, cols kc..+15
    const int vkp = tid & 31, vdg = (tid >> 5) * 8;  // V: keys 2vkp,2vkp+1, d vdg..+7
    const u16* baseK = qkv + (size_t)(b * T + kr) * C3 + C + h * 64 + kc;
    const u16* baseV = qkv + (size_t)(b * T + 2 * vkp) * C3 + 2 * C + h * 64 + vdg;

    u16* plrow = &Pl[w][0][0];

    for (int kt = 0; kt <= qtB; kt++) {
        const int kt0 = kt * 64;
        __syncthreads();   // previous tile's LDS reads complete
        {
            const uint4* gp = reinterpret_cast<const uint4*>(baseK + (size_t)kt0 * C3);
            uint4 ka = gp[0], kb = gp[1];
            const u16* g0 = baseV + (size_t)kt0 * C3;
            uint4 va = *reinterpret_cast<const uint4*>(g0);
            uint4 vb = *reinterpret_cast<const uint4*>(g0 + C3);
            *reinterpret_cast<uint4*>(&Ks[kr][kc])     = ka;
            *reinterpret_cast<uint4*>(&Ks[kr][kc + 8]) = kb;
            const u16* p0 = reinterpret_cast<const u16*>(&va);
            const u16* p1 = reinterpret_cast<const u16*>(&vb);
#pragma unroll
            for (int i = 0; i < 8; i++)
                *reinterpret_cast<u32*>(&Vt[vdg + i][2 * vkp]) =
                    (u32)p0[i] | ((u32)p1[i] << 16);
        }
        __syncthreads();

        tile_pass(Ks, Vt, plrow, B, kt0, kt == qtB, quad, c16);
        if (kt <= qtA)
            tile_pass(Ks, Vt, plrow, A, kt0, kt == qtA, quad, c16);
    }

    // ---- epilogue: O rows are q = quad*4 + r, cols d = dsub*16 + c16
    const float invA = 1.0f / A.l;
    const float invB = 1.0f / B.l;
#pragma unroll
    for (int r = 0; r < 4; r++) {
        const float iAr = __shfl(invA, quad * 4 + r);
        const float iBr = __shfl(invB, quad * 4 + r);
        const int qA = qtA * 64 + w * 16 + quad * 4 + r;
        const int qB = qtB * 64 + w * 16 + quad * 4 + r;
#pragma unroll
        for (int dsub = 0; dsub < 4; dsub++) {
            out[(size_t)(b * T + qA) * C + h * 64 + dsub * 16 + c16] =
                f2b(A.O[dsub][r] * iAr);
            out[(size_t)(b * T + qB) * C + h * 64 + dsub * 16 + c16] =
                f2b(B.O[dsub][r] * iBr);
        }
    }
}

// ---------- launcher ----------
extern "C" void kernel_launch(void* const* d_in, const int* in_sizes, int n_in,
                              void* d_out, int out_size, void* d_ws, size_t ws_size,
                              hipStream_t stream)
{
    constexpr int B = 4, T = 2048, C = 1024;
    constexpr int M = B * T;          // 8192
    const float* x      = (const float*)d_in[0];
    const float* W_attn = (const float*)d_in[1];
    const float* b_attn = (const float*)d_in[2];
    const float* W_proj = (const float*)d_in[3];
    const float* b_proj = (const float*)d_in[4];
    float* out = (float*)d_out;

    // workspace layout: qkv | {xb / attn_o aliased} | Wt_attn | Wt_proj
    char* p = (char*)d_ws;
    u16* qkv     = (u16*)p;                 p += (size_t)M * 3 * C * sizeof(u16);
    u16* xb      = (u16*)p;
    u16* attn_o  = (u16*)p;                 p += (size_t)M * C * sizeof(u16);
    u16* Wt_attn = (u16*)p;                 p += (size_t)3 * C * C * sizeof(u16);
    u16* Wt_proj = (u16*)p;

    cast_bf16<<<dim3(M * C / (256 * 8)), 256, 0, stream>>>(x, xb, M * C);
    transpose_cast<<<dim3(3 * C / 32, C / 32), 256, 0, stream>>>(W_attn, Wt_attn, C, 3 * C);
    transpose_cast<<<dim3(C / 32, C / 32), 256, 0, stream>>>(W_proj, Wt_proj, C, C);

    gemm_mfma<u16><<<dim3(3 * C / 128, M / 128), 256, 0, stream>>>(
        xb, Wt_attn, b_attn, qkv, M, 3 * C, C);

    attn_flash<<<dim3(16, B * 16), 256, 0, stream>>>(qkv, attn_o);

    gemm_mfma<float><<<dim3(C / 128, M / 128), 256, 0, stream>>>(
        attn_o, Wt_proj, b_proj, out, M, C, C);
}